// Round 1
// baseline (229.606 us; speedup 1.0000x reference)
//
#include <hip/hip_runtime.h>

// VectorQuantization: N=65536 vectors, D=64, K=512 codebook.
// outputs: quantized_st [4194304] floats, loss [1], perplexity [1]
// ws layout (floats): [0..511] sq_e, [512] loss_sum, [1024..1535] counts (as uint)

#define VQ_N 65536
#define VQ_D 64
#define VQ_K 512

// --- Kernel A: precompute |e_k|^2, zero accumulators -----------------------
__global__ void vq_prep(const float* __restrict__ cb,
                        float* __restrict__ ws_f,
                        unsigned* __restrict__ counts) {
    int t = threadIdx.x;  // 512 threads, 1 block
    counts[t] = 0u;
    if (t == 0) ws_f[512] = 0.0f;
    const float4* row = reinterpret_cast<const float4*>(cb + t * VQ_D);
    float s = 0.0f;
#pragma unroll
    for (int i = 0; i < VQ_D / 4; ++i) {
        float4 v = row[i];
        s += v.x * v.x + v.y * v.y + v.z * v.z + v.w * v.w;
    }
    ws_f[t] = s;
}

// --- Kernel B: argmin + gather + loss partial + histogram ------------------
__global__ __launch_bounds__(256) void vq_main(const float* __restrict__ x,
                                               const float* __restrict__ cb,
                                               const float* __restrict__ sq_e,
                                               float* __restrict__ out,
                                               float* __restrict__ loss_sum,
                                               unsigned* __restrict__ counts) {
    __shared__ unsigned lcounts[VQ_K];
    __shared__ float wsum[4];

    int t = threadIdx.x;
    lcounts[t] = 0u;
    lcounts[t + 256] = 0u;
    __syncthreads();

    int vec = blockIdx.x * 256 + t;  // grid is exactly N/256 = 256 blocks
    const float* xr = x + (size_t)vec * VQ_D;

    // load x row into registers (static indices -> VGPRs)
    float xv[VQ_D];
#pragma unroll
    for (int i = 0; i < VQ_D / 4; ++i) {
        float4 v = reinterpret_cast<const float4*>(xr)[i];
        xv[4 * i + 0] = v.x;
        xv[4 * i + 1] = v.y;
        xv[4 * i + 2] = v.z;
        xv[4 * i + 3] = v.w;
    }

    // argmin over K codewords; dist = |e|^2 - 2 x.e  (|x|^2 is common-mode)
    float bestd = 3.4e38f;
    int bestk = 0;
    for (int k = 0; k < VQ_K; ++k) {
        const float* e = cb + k * VQ_D;  // wave-uniform address -> s_load
        float a0 = 0.0f, a1 = 0.0f, a2 = 0.0f, a3 = 0.0f;
#pragma unroll
        for (int d = 0; d < VQ_D; d += 4) {
            a0 = fmaf(xv[d + 0], e[d + 0], a0);
            a1 = fmaf(xv[d + 1], e[d + 1], a1);
            a2 = fmaf(xv[d + 2], e[d + 2], a2);
            a3 = fmaf(xv[d + 3], e[d + 3], a3);
        }
        float dot = (a0 + a1) + (a2 + a3);
        float dist = fmaf(-2.0f, dot, sq_e[k]);
        if (dist < bestd) {  // strict < keeps first occurrence (np.argmin)
            bestd = dist;
            bestk = k;
        }
    }

    // gather quantized row, write output, accumulate squared error
    const float4* q = reinterpret_cast<const float4*>(cb + (size_t)bestk * VQ_D);
    float4* o = reinterpret_cast<float4*>(out + (size_t)vec * VQ_D);
    float ls = 0.0f;
#pragma unroll
    for (int i = 0; i < VQ_D / 4; ++i) {
        float4 qv = q[i];
        float dx = qv.x - xv[4 * i + 0];
        float dy = qv.y - xv[4 * i + 1];
        float dz = qv.z - xv[4 * i + 2];
        float dw = qv.w - xv[4 * i + 3];
        ls += dx * dx + dy * dy + dz * dz + dw * dw;
        o[i] = qv;
    }

    atomicAdd(&lcounts[bestk], 1u);

    // wave -> block reduce of loss partial
#pragma unroll
    for (int off = 32; off; off >>= 1) ls += __shfl_down(ls, off);
    int wave = t >> 6, lane = t & 63;
    if (lane == 0) wsum[wave] = ls;
    __syncthreads();
    if (t == 0) atomicAdd(loss_sum, (wsum[0] + wsum[1]) + (wsum[2] + wsum[3]));

    // flush histogram
    unsigned c0 = lcounts[t];
    unsigned c1 = lcounts[t + 256];
    if (c0) atomicAdd(&counts[t], c0);
    if (c1) atomicAdd(&counts[t + 256], c1);
}

// --- Kernel C: loss & perplexity scalars -----------------------------------
__global__ void vq_final(const unsigned* __restrict__ counts,
                         const float* __restrict__ loss_sum,
                         float* __restrict__ out_tail) {
    int t = threadIdx.x;  // 512 threads, 1 block
    float p = (float)counts[t] * (1.0f / (float)VQ_N);
    float term = p * logf(p + 1e-10f);
#pragma unroll
    for (int off = 32; off; off >>= 1) term += __shfl_down(term, off);
    __shared__ float wsum[8];
    int wave = t >> 6, lane = t & 63;
    if (lane == 0) wsum[wave] = term;
    __syncthreads();
    if (t == 0) {
        float H = 0.0f;
#pragma unroll
        for (int i = 0; i < 8; ++i) H += wsum[i];
        // loss = (1 + 0.25) * mean((q - x)^2) over N*D elements
        out_tail[0] = loss_sum[0] * (1.25f / (float)(VQ_N * VQ_D));
        out_tail[1] = expf(-H);
    }
}

extern "C" void kernel_launch(void* const* d_in, const int* in_sizes, int n_in,
                              void* d_out, int out_size, void* d_ws, size_t ws_size,
                              hipStream_t stream) {
    const float* x = (const float*)d_in[0];   // [64,32,32,64] fp32
    const float* cb = (const float*)d_in[1];  // [512,64] fp32
    float* out = (float*)d_out;               // [4194304 + 2]
    float* wsf = (float*)d_ws;
    float* sq_e = wsf;
    float* loss = wsf + 512;
    unsigned* counts = (unsigned*)(wsf + 1024);

    vq_prep<<<1, VQ_K, 0, stream>>>(cb, wsf, counts);
    vq_main<<<VQ_N / 256, 256, 0, stream>>>(x, cb, sq_e, out, loss, counts);
    vq_final<<<1, VQ_K, 0, stream>>>(counts, loss, out + (size_t)VQ_N * VQ_D);
}

// Round 2
// 122.968 us; speedup vs baseline: 1.8672x; 1.8672x over previous
//
#include <hip/hip_runtime.h>
#include <stdint.h>

// VectorQuantization: N=65536 vectors, D=64, K=512 codebook.
// outputs: quantized_st [4194304] floats, loss [1], perplexity [1]

#define VQ_N 65536
#define VQ_D 64
#define VQ_K 512

__device__ __forceinline__ unsigned mono_f32(float f) {
    unsigned u = __float_as_uint(f);
    return (u & 0x80000000u) ? ~u : (u | 0x80000000u);
}
__device__ __forceinline__ float unmono_f32(unsigned m) {
    unsigned u = (m & 0x80000000u) ? (m ^ 0x80000000u) : ~m;
    return __uint_as_float(u);
}

// --- Kernel A: |e_k|^2, zero loss/counts -----------------------------------
__global__ void vq_prep(const float* __restrict__ cb,
                        float* __restrict__ sq_e,
                        float* __restrict__ loss_sum,
                        unsigned* __restrict__ counts) {
    int t = threadIdx.x;  // 512 threads, 1 block
    counts[t] = 0u;
    if (t == 0) loss_sum[0] = 0.0f;
    const float4* row = reinterpret_cast<const float4*>(cb + t * VQ_D);
    float s = 0.0f;
#pragma unroll
    for (int i = 0; i < VQ_D / 4; ++i) {
        float4 v = row[i];
        s += v.x * v.x + v.y * v.y + v.z * v.z + v.w * v.w;
    }
    sq_e[t] = s;
}

// --- Kernel B: split-K argmin. Each block handles 256 vectors x one K-chunk.
__global__ __launch_bounds__(256, 4) void vq_pass1(const float* __restrict__ x,
                                                   const float* __restrict__ cb,
                                                   const float* __restrict__ sq_e,
                                                   unsigned long long* __restrict__ cand,
                                                   float* __restrict__ sq_x,
                                                   int chunkK) {
    int t = threadIdx.x;
    int vec = blockIdx.x * 256 + t;
    int chunk = blockIdx.y;
    int k0 = chunk * chunkK;

    const float* xr = x + (size_t)vec * VQ_D;
    float xv[VQ_D];
#pragma unroll
    for (int i = 0; i < VQ_D / 4; ++i) {
        float4 v = reinterpret_cast<const float4*>(xr)[i];
        xv[4 * i + 0] = v.x;
        xv[4 * i + 1] = v.y;
        xv[4 * i + 2] = v.z;
        xv[4 * i + 3] = v.w;
    }
    if (chunk == 0) {
        float s = 0.0f;
#pragma unroll
        for (int i = 0; i < VQ_D; ++i) s = fmaf(xv[i], xv[i], s);
        sq_x[vec] = s;
    }

    float bestd = 3.4e38f;
    int bestk = k0;
    for (int kk = 0; kk < chunkK; ++kk) {
        int k = k0 + kk;
        const float* e = cb + (size_t)k * VQ_D;  // wave-uniform -> s_load
        float a0 = 0.0f, a1 = 0.0f, a2 = 0.0f, a3 = 0.0f;
#pragma unroll
        for (int d = 0; d < VQ_D; d += 4) {
            a0 = fmaf(xv[d + 0], e[d + 0], a0);
            a1 = fmaf(xv[d + 1], e[d + 1], a1);
            a2 = fmaf(xv[d + 2], e[d + 2], a2);
            a3 = fmaf(xv[d + 3], e[d + 3], a3);
        }
        float dot = (a0 + a1) + (a2 + a3);
        float dist = fmaf(-2.0f, dot, sq_e[k]);
        if (dist < bestd) {  // strict < == np.argmin first-occurrence
            bestd = dist;
            bestk = k;
        }
    }
    // pack: min over u64 == (min dist, then min k) -- chunk order == k order
    cand[(size_t)chunk * VQ_N + vec] =
        ((unsigned long long)mono_f32(bestd) << 32) | (unsigned)bestk;
}

// --- Kernel C: combine candidates, gather, loss, histogram -----------------
__global__ __launch_bounds__(256) void vq_pass2(const float* __restrict__ cb,
                                                const unsigned long long* __restrict__ cand,
                                                const float* __restrict__ sq_x,
                                                float* __restrict__ out,
                                                float* __restrict__ loss_sum,
                                                unsigned* __restrict__ counts,
                                                int ksplit) {
    __shared__ unsigned lcounts[VQ_K];
    __shared__ float wsum[4];
    int t = threadIdx.x;
    lcounts[t] = 0u;
    lcounts[t + 256] = 0u;
    __syncthreads();

    int vec = blockIdx.x * 256 + t;
    unsigned long long best = cand[vec];
    for (int c = 1; c < ksplit; ++c) {
        unsigned long long v = cand[(size_t)c * VQ_N + vec];
        if (v < best) best = v;
    }
    int bestk = (int)(best & 0xffffffffull);
    float bestd = unmono_f32((unsigned)(best >> 32));

    // |x - e|^2 = |x|^2 + (|e|^2 - 2 x.e) = sq_x + bestd
    float ls = sq_x[vec] + bestd;

    const float4* q = reinterpret_cast<const float4*>(cb + (size_t)bestk * VQ_D);
    float4* o = reinterpret_cast<float4*>(out + (size_t)vec * VQ_D);
#pragma unroll
    for (int i = 0; i < VQ_D / 4; ++i) o[i] = q[i];

    atomicAdd(&lcounts[bestk], 1u);

#pragma unroll
    for (int off = 32; off; off >>= 1) ls += __shfl_down(ls, off);
    int wave = t >> 6, lane = t & 63;
    if (lane == 0) wsum[wave] = ls;
    __syncthreads();
    if (t == 0) atomicAdd(loss_sum, (wsum[0] + wsum[1]) + (wsum[2] + wsum[3]));

    unsigned c0 = lcounts[t];
    unsigned c1 = lcounts[t + 256];
    if (c0) atomicAdd(&counts[t], c0);
    if (c1) atomicAdd(&counts[t + 256], c1);
}

// --- Kernel D: loss & perplexity scalars -----------------------------------
__global__ void vq_final(const unsigned* __restrict__ counts,
                         const float* __restrict__ loss_sum,
                         float* __restrict__ out_tail) {
    int t = threadIdx.x;  // 512 threads, 1 block
    float p = (float)counts[t] * (1.0f / (float)VQ_N);
    float term = p * logf(p + 1e-10f);
#pragma unroll
    for (int off = 32; off; off >>= 1) term += __shfl_down(term, off);
    __shared__ float wsum[8];
    int wave = t >> 6, lane = t & 63;
    if (lane == 0) wsum[wave] = term;
    __syncthreads();
    if (t == 0) {
        float H = 0.0f;
#pragma unroll
        for (int i = 0; i < 8; ++i) H += wsum[i];
        out_tail[0] = loss_sum[0] * (1.25f / (float)(VQ_N * VQ_D));
        out_tail[1] = expf(-H);
    }
}

extern "C" void kernel_launch(void* const* d_in, const int* in_sizes, int n_in,
                              void* d_out, int out_size, void* d_ws, size_t ws_size,
                              hipStream_t stream) {
    const float* x = (const float*)d_in[0];   // [64,32,32,64] fp32
    const float* cb = (const float*)d_in[1];  // [512,64] fp32
    float* out = (float*)d_out;               // [4194304 + 2]

    // pick largest ksplit whose candidate buffer fits in ws
    int ksplit = 8;
    while (ksplit > 1 &&
           (size_t)ksplit * VQ_N * 8 + 4 * (512 + VQ_N + 1 + 512) > ws_size)
        ksplit >>= 1;
    int chunkK = VQ_K / ksplit;

    unsigned long long* cand = (unsigned long long*)d_ws;
    float* sq_e = (float*)((char*)d_ws + (size_t)ksplit * VQ_N * 8);
    float* sq_x = sq_e + 512;
    float* loss = sq_x + VQ_N;
    unsigned* counts = (unsigned*)(loss + 1);

    vq_prep<<<1, VQ_K, 0, stream>>>(cb, sq_e, loss, counts);
    vq_pass1<<<dim3(VQ_N / 256, ksplit), 256, 0, stream>>>(x, cb, sq_e, cand, sq_x, chunkK);
    vq_pass2<<<VQ_N / 256, 256, 0, stream>>>(cb, cand, sq_x, out, loss, counts, ksplit);
    vq_final<<<1, VQ_K, 0, stream>>>(counts, loss, out + (size_t)VQ_N * VQ_D);
}

// Round 3
// 58.434 us; speedup vs baseline: 3.9293x; 2.1044x over previous
//
#include <hip/hip_runtime.h>
#include <stdint.h>

// VectorQuantization via bf16 split-MFMA: N=65536, D=64, K=512.
// dot(x,e) = xh*eh + xh*el + xl*eh  (drop xl*el, err ~5e-7)
// dist = |e|^2 - 2 dot  (|x|^2 common-mode for argmin; added back for loss)

#define VQ_N 65536
#define VQ_D 64
#define VQ_K 512

typedef __attribute__((ext_vector_type(4))) float f32x4;
typedef __attribute__((ext_vector_type(8))) short bf16x8;

__device__ __forceinline__ unsigned mono_f32(float f) {
    unsigned u = __float_as_uint(f);
    return (u & 0x80000000u) ? ~u : (u | 0x80000000u);
}
__device__ __forceinline__ float unmono_f32(unsigned m) {
    unsigned u = (m & 0x80000000u) ? (m ^ 0x80000000u) : ~m;
    return __uint_as_float(u);
}
__device__ __forceinline__ unsigned short f2bf(float f) {  // RNE
    unsigned b = __float_as_uint(f);
    return (unsigned short)((b + 0x7fffu + ((b >> 16) & 1u)) >> 16);
}

// --- Kernel A: pack codebook into B-fragment order (hi/lo), sq_e, zeros ----
// B frag entry (ct,kt,part,lane): 8 bf16, col=ct*16+(lane&15), k=kt*32+(lane>>4)*8+j
__global__ __launch_bounds__(256) void vq_prep(const float* __restrict__ cb,
                                               unsigned short* __restrict__ Bfrag,
                                               float* __restrict__ sq_e,
                                               float* __restrict__ loss_sum,
                                               unsigned* __restrict__ counts) {
    int g = blockIdx.x * 256 + threadIdx.x;  // 4096 threads
    int lane = g & 63, kt = (g >> 6) & 1, ct = g >> 7;
    int col = ct * 16 + (lane & 15);
    int k0 = kt * 32 + (lane >> 4) * 8;
    const float4* p = reinterpret_cast<const float4*>(cb + (size_t)col * VQ_D + k0);
    float4 v0 = p[0], v1 = p[1];
    float vv[8] = {v0.x, v0.y, v0.z, v0.w, v1.x, v1.y, v1.z, v1.w};
    bf16x8 h, lo;
#pragma unroll
    for (int j = 0; j < 8; ++j) {
        unsigned short hu = f2bf(vv[j]);
        float hf = __uint_as_float((unsigned)hu << 16);
        h[j] = (short)hu;
        lo[j] = (short)f2bf(vv[j] - hf);
    }
    size_t base = ((size_t)(ct * 2 + kt) * 2) * 64 + lane;
    *reinterpret_cast<bf16x8*>(&Bfrag[(base)*8]) = h;
    *reinterpret_cast<bf16x8*>(&Bfrag[(base + 64) * 8]) = lo;  // part=1

    if (g < VQ_K) {
        const float4* row = reinterpret_cast<const float4*>(cb + (size_t)g * VQ_D);
        float s = 0.0f;
#pragma unroll
        for (int i = 0; i < VQ_D / 4; ++i) {
            float4 v = row[i];
            s += v.x * v.x + v.y * v.y + v.z * v.z + v.w * v.w;
        }
        sq_e[g] = s;
        counts[g] = 0u;
        if (g == 0) loss_sum[0] = 0.0f;
    }
}

// --- Kernel B: MFMA distances + fused per-row argmin ------------------------
// 256 blocks x 256 thr (4 waves). Wave owns 64 rows; all 512 cols streamed.
__global__ __launch_bounds__(256, 1) void vq_mfma(const float* __restrict__ x,
                                                  const unsigned short* __restrict__ Bfrag,
                                                  const float* __restrict__ sq_e,
                                                  unsigned long long* __restrict__ cand,
                                                  float* __restrict__ sq_x) {
    __shared__ unsigned short lds[32768];  // 64 KB = half the codebook frags
    int t = threadIdx.x;
    int w = t >> 6, l = t & 63;
    int lr = l & 15, lg = l >> 4;
    int rowbase = blockIdx.x * 256 + w * 64;

    // load x rows -> A frags (hi/lo) + sq_x
    bf16x8 Ahi[4][2], Alo[4][2];
#pragma unroll
    for (int rt = 0; rt < 4; ++rt) {
        float part = 0.0f;
#pragma unroll
        for (int kt = 0; kt < 2; ++kt) {
            const float4* p = reinterpret_cast<const float4*>(
                x + (size_t)(rowbase + rt * 16 + lr) * VQ_D + kt * 32 + lg * 8);
            float4 v0 = p[0], v1 = p[1];
            float vv[8] = {v0.x, v0.y, v0.z, v0.w, v1.x, v1.y, v1.z, v1.w};
            bf16x8 h, lo;
#pragma unroll
            for (int j = 0; j < 8; ++j) {
                unsigned short hu = f2bf(vv[j]);
                float hf = __uint_as_float((unsigned)hu << 16);
                h[j] = (short)hu;
                lo[j] = (short)f2bf(vv[j] - hf);
                part = fmaf(vv[j], vv[j], part);
            }
            Ahi[rt][kt] = h;
            Alo[rt][kt] = lo;
        }
        part += __shfl_xor(part, 16);
        part += __shfl_xor(part, 32);
        if (lg == 0) sq_x[rowbase + rt * 16 + lr] = part;
    }

    float bd[4][4];
    int bc[4][4];
#pragma unroll
    for (int rt = 0; rt < 4; ++rt)
#pragma unroll
        for (int j = 0; j < 4; ++j) {
            bd[rt][j] = 3.4e38f;
            bc[rt][j] = 0;
        }

    for (int half = 0; half < 2; ++half) {
        __syncthreads();  // prior reads done before overwrite
#pragma unroll
        for (int i = 0; i < 16; ++i) {  // stage 64 KB (cols half*256..+256)
            int idx = (i * 256 + t) * 8;
            *reinterpret_cast<bf16x8*>(&lds[idx]) =
                *reinterpret_cast<const bf16x8*>(&Bfrag[(size_t)half * 32768 + idx]);
        }
        __syncthreads();

        for (int sub = 0; sub < 2; ++sub) {  // 128-col chunk
            f32x4 acc[4][8];
#pragma unroll
            for (int rt = 0; rt < 4; ++rt)
#pragma unroll
                for (int c = 0; c < 8; ++c) acc[rt][c] = (f32x4){0.f, 0.f, 0.f, 0.f};

#pragma unroll
            for (int ct2 = 0; ct2 < 8; ++ct2) {
#pragma unroll
                for (int kt = 0; kt < 2; ++kt) {
                    int ctl = sub * 8 + ct2;
                    const bf16x8* bp = reinterpret_cast<const bf16x8*>(
                        &lds[(((ctl * 2 + kt) * 2) * 64 + l) * 8]);
                    bf16x8 bh = bp[0];
                    bf16x8 bl = bp[64];  // part=1 is 64 entries later
#pragma unroll
                    for (int rt = 0; rt < 4; ++rt) {
                        acc[rt][ct2] = __builtin_amdgcn_mfma_f32_16x16x32_bf16(
                            Ahi[rt][kt], bh, acc[rt][ct2], 0, 0, 0);
                        acc[rt][ct2] = __builtin_amdgcn_mfma_f32_16x16x32_bf16(
                            Ahi[rt][kt], bl, acc[rt][ct2], 0, 0, 0);
                        acc[rt][ct2] = __builtin_amdgcn_mfma_f32_16x16x32_bf16(
                            Alo[rt][kt], bh, acc[rt][ct2], 0, 0, 0);
                    }
                }
            }
            // running argmin over this 128-col chunk (cols ascend -> strict <)
            int colbase = (half * 2 + sub) * 128;
#pragma unroll
            for (int ct2 = 0; ct2 < 8; ++ct2) {
                int col = colbase + ct2 * 16 + lr;
                float se = sq_e[col];
#pragma unroll
                for (int rt = 0; rt < 4; ++rt)
#pragma unroll
                    for (int j = 0; j < 4; ++j) {
                        float d = fmaf(-2.0f, acc[rt][ct2][j], se);
                        if (d < bd[rt][j]) {
                            bd[rt][j] = d;
                            bc[rt][j] = col;
                        }
                    }
            }
        }
    }

    // cross-lane (16 cols) argmin butterfly; ties -> smaller col
#pragma unroll
    for (int rt = 0; rt < 4; ++rt)
#pragma unroll
        for (int j = 0; j < 4; ++j) {
            float d = bd[rt][j];
            int c = bc[rt][j];
#pragma unroll
            for (int off = 1; off <= 8; off <<= 1) {
                float od = __shfl_xor(d, off);
                int oc = __shfl_xor(c, off);
                if (od < d || (od == d && oc < c)) {
                    d = od;
                    c = oc;
                }
            }
            if (lr == 0) {
                int row = rowbase + rt * 16 + lg * 4 + j;
                cand[row] = ((unsigned long long)mono_f32(d) << 32) | (unsigned)c;
            }
        }
}

// --- Kernel C: gather + loss + histogram ------------------------------------
__global__ __launch_bounds__(256) void vq_pass2(const float* __restrict__ cb,
                                                const unsigned long long* __restrict__ cand,
                                                const float* __restrict__ sq_x,
                                                float* __restrict__ out,
                                                float* __restrict__ loss_sum,
                                                unsigned* __restrict__ counts) {
    __shared__ unsigned lcounts[VQ_K];
    __shared__ float wsum[4];
    int t = threadIdx.x;
    lcounts[t] = 0u;
    lcounts[t + 256] = 0u;
    __syncthreads();

    int vec = blockIdx.x * 256 + t;
    unsigned long long best = cand[vec];
    int bestk = (int)(best & 0xffffffffull);
    float bestd = unmono_f32((unsigned)(best >> 32));
    float ls = sq_x[vec] + bestd;  // |x-e|^2

    const float4* q = reinterpret_cast<const float4*>(cb + (size_t)bestk * VQ_D);
    float4* o = reinterpret_cast<float4*>(out + (size_t)vec * VQ_D);
#pragma unroll
    for (int i = 0; i < VQ_D / 4; ++i) o[i] = q[i];

    atomicAdd(&lcounts[bestk], 1u);

#pragma unroll
    for (int off = 32; off; off >>= 1) ls += __shfl_down(ls, off);
    int wave = t >> 6, lane = t & 63;
    if (lane == 0) wsum[wave] = ls;
    __syncthreads();
    if (t == 0) atomicAdd(loss_sum, (wsum[0] + wsum[1]) + (wsum[2] + wsum[3]));

    unsigned c0 = lcounts[t];
    unsigned c1 = lcounts[t + 256];
    if (c0) atomicAdd(&counts[t], c0);
    if (c1) atomicAdd(&counts[t + 256], c1);
}

// --- Kernel D: loss & perplexity scalars -------------------------------------
__global__ void vq_final(const unsigned* __restrict__ counts,
                         const float* __restrict__ loss_sum,
                         float* __restrict__ out_tail) {
    int t = threadIdx.x;  // 512 threads
    float p = (float)counts[t] * (1.0f / (float)VQ_N);
    float term = p * logf(p + 1e-10f);
#pragma unroll
    for (int off = 32; off; off >>= 1) term += __shfl_down(term, off);
    __shared__ float wsum[8];
    int wave = t >> 6, lane = t & 63;
    if (lane == 0) wsum[wave] = term;
    __syncthreads();
    if (t == 0) {
        float H = 0.0f;
#pragma unroll
        for (int i = 0; i < 8; ++i) H += wsum[i];
        out_tail[0] = loss_sum[0] * (1.25f / (float)(VQ_N * VQ_D));
        out_tail[1] = expf(-H);
    }
}

extern "C" void kernel_launch(void* const* d_in, const int* in_sizes, int n_in,
                              void* d_out, int out_size, void* d_ws, size_t ws_size,
                              hipStream_t stream) {
    const float* x = (const float*)d_in[0];   // [65536,64] fp32
    const float* cb = (const float*)d_in[1];  // [512,64] fp32
    float* out = (float*)d_out;               // [4194304 + 2]

    // ws: Bfrag 128KB | cand 512KB | sq_e 2KB | sq_x 256KB | loss 4B | counts 2KB
    unsigned short* Bfrag = (unsigned short*)d_ws;
    unsigned long long* cand = (unsigned long long*)((char*)d_ws + (128 << 10));
    float* sq_e = (float*)((char*)d_ws + (640 << 10));
    float* sq_x = sq_e + 512;
    float* loss = sq_x + VQ_N;
    unsigned* counts = (unsigned*)(loss + 1);

    vq_prep<<<16, 256, 0, stream>>>(cb, Bfrag, sq_e, loss, counts);
    vq_mfma<<<VQ_N / 256, 256, 0, stream>>>(x, Bfrag, sq_e, cand, sq_x);
    vq_pass2<<<VQ_N / 256, 256, 0, stream>>>(cb, cand, sq_x, out, loss, counts);
    vq_final<<<1, VQ_K, 0, stream>>>(counts, loss, out + (size_t)VQ_N * VQ_D);
}